// Round 13
// baseline (59.230 us; speedup 1.0000x reference)
//
#include <hip/hip_runtime.h>

#define LOG2E 1.4426950408889634f
#define EXP2(x) __builtin_amdgcn_exp2f(x)   // bare v_exp_f32 (no ocml fixup)

typedef __attribute__((ext_vector_type(4))) float f32x4;
typedef __attribute__((ext_vector_type(4))) short s16x4;
typedef __attribute__((ext_vector_type(8))) short s16x8;
typedef __attribute__((ext_vector_type(4))) __bf16 bf16x4;
typedef __attribute__((ext_vector_type(8))) __bf16 bf16x8;

// B=2 S=2048 H=16 D=64, fp32 in/out.
#define SS 2048
#define HH 16
#define DD 64
#define HSZ (HH * DD)
#define BHSZ (SS * DD)  // 131072 elems per (b,h) plane

// ---- fused prep: K -> Kf fragment-major bf16, V -> Vf fragment-major -----
// Kf[bh][sub][c][lane][j]: lane l -> K[key=sub*16+(l&15)][d=c*32+(l>>4)*8+j]
// Vf[bh][sub][nb][lane][j]: lane l -> V[key=sub*16+(l>>4)*4+j][d=nb*16+(l&15)]
__global__ __launch_bounds__(256) void prep_kv(const float* __restrict__ Kg,
                                               const float* __restrict__ Vg,
                                               short* __restrict__ Kf,
                                               short* __restrict__ Vf) {
  const int blk = blockIdx.x;
  if (blk < 2048) {  // ---- K part: 524,288 16B chunks
    const int idx = blk * 256 + threadIdx.x;
    const int l  = idx & 63;
    const int c  = (idx >> 6) & 1;
    const int s  = (idx >> 7) & 127;
    const int bh = idx >> 14;
    const int b = bh >> 4, h = bh & 15;
    const int key = (s << 4) + (l & 15);
    const int d0  = (c << 5) + ((l >> 4) << 3);
    const float* src = Kg + (((size_t)b * SS + key) * HH + h) * DD + d0;
    f32x4 a = *(const f32x4*)(src);
    f32x4 b2 = *(const f32x4*)(src + 4);
    bf16x8 o;
#pragma unroll
    for (int j = 0; j < 4; ++j) {
      o[j] = (__bf16)a[j];
      o[4 + j] = (__bf16)b2[j];
    }
    *(s16x8*)(Kf + (size_t)idx * 8) = __builtin_bit_cast(s16x8, o);
  } else {           // ---- V part: 1,048,576 8B chunks
    const int idx = (blk - 2048) * 256 + threadIdx.x;
    const int l  = idx & 63;
    const int nb = (idx >> 6) & 3;
    const int s  = (idx >> 8) & 127;
    const int bh = idx >> 15;
    const int b = bh >> 4, h = bh & 15;
    const int d    = (nb << 4) + (l & 15);
    const int key0 = (s << 4) + ((l >> 4) << 2);
    const float* src = Vg + (((size_t)b * SS + key0) * HH + h) * DD + d;
    bf16x4 o;
#pragma unroll
    for (int j = 0; j < 4; ++j) o[j] = (__bf16)src[(size_t)j * HSZ];
    *(s16x4*)(Vf + (size_t)idx * 4) = __builtin_bit_cast(s16x4, o);
  }
}

// ---- main: 8-wave balanced persistent pairs, 8-way split-K ---------------
// 1024 blocks x 512 threads (8 waves). Block processes q-pair u=63-v then
// u=v SEQUENTIALLY; each pass: all 8 waves split the key range (empty
// shares for tiny u are fine: zero partials + pure-sum merge). Per-block
// iterations ~16.5 const -> all blocks equal-time; 4 blocks/CU x 8 waves =
// 32 waves/CU nominal (fixes R12's 50% occupancy cap from 4-wave blocks).
// Resources: LDS 34.8KB x 4 = 139KB <= 160KB; VGPR 48 x 8 waves/SIMD x 64
// = 384 <= 512/SIMD. Static-base softmax (R9+), raw v_exp_f32 (R12: halved
// the VALU integral). XCD-local bh. Launch bounds (512,4): never force a
// VGPR cap below live state (R7 spill: 870MB scratch, 5x).

#define SOFTPV(stv, M, ll, oacc)                                             \
  {                                                                          \
    if (M) {                                                                 \
      _Pragma("unroll") for (int r = 0; r < 4; ++r)                          \
          if (g * 4 + r > lm) stv[r] = -1e30f;                               \
    }                                                                        \
    f32x4 p;                                                                 \
    _Pragma("unroll") for (int r = 0; r < 4; ++r) p[r] = EXP2(stv[r]);       \
    ll += (p[0] + p[1]) + (p[2] + p[3]);                                     \
    bf16x4 pb;                                                               \
    _Pragma("unroll") for (int r = 0; r < 4; ++r) pb[r] = (__bf16)p[r];      \
    const s16x4 pf = __builtin_bit_cast(s16x4, pb);                          \
    oacc[0] = __builtin_amdgcn_mfma_f32_16x16x16bf16_1k(vv0, pf, oacc[0], 0, 0, 0); \
    oacc[1] = __builtin_amdgcn_mfma_f32_16x16x16bf16_1k(vv1, pf, oacc[1], 0, 0, 0); \
    oacc[2] = __builtin_amdgcn_mfma_f32_16x16x16bf16_1k(vv2, pf, oacc[2], 0, 0, 0); \
    oacc[3] = __builtin_amdgcn_mfma_f32_16x16x16bf16_1k(vv3, pf, oacc[3], 0, 0, 0); \
  }

// DO0/DO1: process tile0/tile1; M0/M1: apply diagonal mask to that tile.
#define SUBTILE2(sub, DO0, M0, DO1, M1)                                      \
  {                                                                          \
    const short* ka = kb2 + ((size_t)(sub) << 10);                           \
    const s16x8 k0 = *(const s16x8*)(ka);                                    \
    const s16x8 k1 = *(const s16x8*)(ka + 512);                              \
    const short* vpp = vb2 + ((size_t)(sub) << 10);                          \
    const s16x4 vv0 = *(const s16x4*)(vpp);                                  \
    const s16x4 vv1 = *(const s16x4*)(vpp + 256);                            \
    const s16x4 vv2 = *(const s16x4*)(vpp + 512);                            \
    const s16x4 vv3 = *(const s16x4*)(vpp + 768);                            \
    if (DO0) {                                                               \
      f32x4 stv = {0, 0, 0, 0};                                              \
      stv = __builtin_amdgcn_mfma_f32_16x16x32_bf16(k0, qf0[0], stv, 0, 0, 0);\
      stv = __builtin_amdgcn_mfma_f32_16x16x32_bf16(k1, qf0[1], stv, 0, 0, 0);\
      SOFTPV(stv, M0, l0, oacc0)                                             \
    }                                                                        \
    if (DO1) {                                                               \
      f32x4 stv = {0, 0, 0, 0};                                              \
      stv = __builtin_amdgcn_mfma_f32_16x16x32_bf16(k0, qf1[0], stv, 0, 0, 0);\
      stv = __builtin_amdgcn_mfma_f32_16x16x32_bf16(k1, qf1[1], stv, 0, 0, 0);\
      SOFTPV(stv, M1, l1, oacc1)                                             \
    }                                                                        \
  }

#define PUBLISH(slot)                                                        \
  {                                                                          \
    _Pragma("unroll") for (int nb = 0; nb < 4; ++nb)                         \
        _Pragma("unroll") for (int r = 0; r < 4; ++r) {                      \
      lo[slot][nb * 4 + r][lane] = oacc0[nb][r];                             \
      lo[slot][16 + nb * 4 + r][lane] = oacc1[nb][r];                        \
    }                                                                        \
    lo[slot][32][lane] = l0;                                                 \
    lo[slot][33][lane] = l1;                                                 \
  }

#define ADDIN(slot)                                                          \
  {                                                                          \
    _Pragma("unroll") for (int nb = 0; nb < 4; ++nb)                         \
        _Pragma("unroll") for (int r = 0; r < 4; ++r) {                      \
      oacc0[nb][r] += lo[slot][nb * 4 + r][lane];                            \
      oacc1[nb][r] += lo[slot][16 + nb * 4 + r][lane];                       \
    }                                                                        \
    l0 += lo[slot][32][lane];                                                \
    l1 += lo[slot][33][lane];                                                \
  }

__device__ __forceinline__ void qpair_pass8(
    const int u, const int w, const int lane, const int lm, const int g,
    const float* __restrict__ Qg, const short* __restrict__ kb2,
    const short* __restrict__ vb2, float* __restrict__ Og,
    const size_t qbase, float (*lo)[34][64])
{
  const int t0 = u << 1, t1 = t0 + 1;
  const int n  = t1 + 1;

  // Q frags for both tiles (B operand of S^T, K=32): d = c*32+g*8+j, scaled
  s16x8 qf0[2], qf1[2];
  {
    const float qs = 0.125f * LOG2E;
#pragma unroll
    for (int x = 0; x < 2; ++x) {
      const float* qp = Qg + qbase + (size_t)(((t0 + x) << 4) + lm) * HSZ + g * 8;
#pragma unroll
      for (int c = 0; c < 2; ++c) {
        f32x4 a = *(const f32x4*)(qp + c * 32);
        f32x4 b2 = *(const f32x4*)(qp + c * 32 + 4);
        bf16x8 bv;
#pragma unroll
        for (int j2 = 0; j2 < 4; ++j2) {
          bv[j2] = (__bf16)(a[j2] * qs);
          bv[4 + j2] = (__bf16)(b2[j2] * qs);
        }
        if (x == 0) qf0[c] = __builtin_bit_cast(s16x8, bv);
        else        qf1[c] = __builtin_bit_cast(s16x8, bv);
      }
    }
  }

  f32x4 oacc0[4] = {{0,0,0,0},{0,0,0,0},{0,0,0,0},{0,0,0,0}};
  f32x4 oacc1[4] = {{0,0,0,0},{0,0,0,0},{0,0,0,0},{0,0,0,0}};
  float l0 = 0.0f, l1 = 0.0f;

  // contiguous eighth [s, e) of the key range for this wave (may be empty)
  const int n8 = n >> 3, rem = n & 7;
  int s = w * n8 + (w < rem ? w : rem);
  const int e = s + n8 + (w < rem ? 1 : 0);

  const int plain_end = (e < t0) ? e : t0;
  for (; s < plain_end; ++s) SUBTILE2(s, 1, 0, 1, 0)
  if (s < e && s == t0) { SUBTILE2(t0, 1, 1, 1, 0) ++s; }  // diag t0
  if (s < e && s == t1) { SUBTILE2(t1, 0, 0, 1, 1) }       // diag t1

  // ---- pure-sum merge: odds publish; evens absorb; 2/4/6 republish;
  // ---- wave 0 sums the rest, normalizes, stores. 3 syncs + trailing.
  if (w & 1) PUBLISH(w >> 1)
  __syncthreads();
  if (w == 0) ADDIN(0)
  if (w == 2) { ADDIN(1) PUBLISH(1) }
  if (w == 4) { ADDIN(2) PUBLISH(2) }
  if (w == 6) { ADDIN(3) PUBLISH(3) }
  __syncthreads();
  if (w == 0) {
    ADDIN(1) ADDIN(2) ADDIN(3)
#pragma unroll
    for (int x = 0; x < 2; ++x) {
      float l = x ? l1 : l0;
      l += __shfl_xor(l, 16);
      l += __shfl_xor(l, 32);
      const float inv = 1.0f / l;
      float* op = Og + qbase + (size_t)(((t0 + x) << 4) + lm) * HSZ + g * 4;
#pragma unroll
      for (int nb = 0; nb < 4; ++nb) {
        f32x4 o;
#pragma unroll
        for (int r = 0; r < 4; ++r)
          o[r] = (x ? oacc1[nb][r] : oacc0[nb][r]) * inv;
        *(f32x4*)(op + nb * 16) = o;
      }
    }
  }
  __syncthreads();  // protect LDS slots before the next pass republishes
}

__global__ __launch_bounds__(512, 4) void attn_fwd13(
    const float* __restrict__ Qg, const short* __restrict__ Kf,
    const short* __restrict__ Vf, float* __restrict__ Og)
{
  __shared__ float lo[4][34][64];  // 4 publish slots [slot][reg][lane]

  const int tid  = threadIdx.x;
  const int lane = tid & 63;
  const int lm   = lane & 15;
  const int g    = lane >> 4;
  const int w    = tid >> 6;    // 0..7: split-K eighth

  // XCD-local mapping: id%8 = XCD (round-robin dispatch heuristic).
  const int id   = blockIdx.x;            // 0..1023
  const int xcd  = id & 7;
  const int r7   = id >> 3;               // 0..127
  const int bh   = (xcd << 2) | (r7 & 3);
  const int v    = r7 >> 2;               // 0..31
  const int uA   = 63 - v;                // heavy pass first
  const int uB   = v;                     // complementary light pass

  const size_t qbase = (size_t)(bh >> 4) * SS * HSZ + (size_t)(bh & 15) * DD;
  const short* kb2 = Kf + (size_t)bh * BHSZ + lane * 8;
  const short* vb2 = Vf + (size_t)bh * BHSZ + lane * 4;

  qpair_pass8(uA, w, lane, lm, g, Qg, kb2, vb2, Og, qbase, lo);
  qpair_pass8(uB, w, lane, lm, g, Qg, kb2, vb2, Og, qbase, lo);
}

// ---- fallback (round-1 kernel) if ws too small ---------------------------
__global__ __launch_bounds__(256) void attn_fwd(
    const float* __restrict__ Qg, const float* __restrict__ Kg,
    const float* __restrict__ Vg, float* __restrict__ Og)
{
  const int tid  = threadIdx.x;
  const int lane = tid & 63;
  const int lm   = lane & 15;
  const int g    = lane >> 4;
  const int w    = tid >> 6;
  const int bh = blockIdx.x;
  const int b  = bh >> 4;
  const int h  = bh & 15;
  const int t  = ((gridDim.y - 1 - blockIdx.y) << 2) | w;
  const int qb = t << 4;
  const size_t base = (size_t)b * SS * HSZ + (size_t)h * DD;
  s16x4 qf[4];
  {
    const float* qp = Qg + base + (size_t)(qb + lm) * HSZ + g * 4;
    const float qs = 0.125f * LOG2E;
#pragma unroll
    for (int c = 0; c < 4; ++c) {
      f32x4 qv = *(const f32x4*)(qp + c * 16);
      bf16x4 bv;
#pragma unroll
      for (int j = 0; j < 4; ++j) bv[j] = (__bf16)(qv[j] * qs);
      qf[c] = __builtin_bit_cast(s16x4, bv);
    }
  }
  f32x4 oacc[4] = {{0,0,0,0},{0,0,0,0},{0,0,0,0},{0,0,0,0}};
  float m = -1e30f, lsum = 0.0f;
  const float* kp = Kg + base + (size_t)lm * HSZ + g * 4;
  const float* vp = Vg + base + (size_t)(g * 4) * HSZ + lm;
  for (int kt = 0; kt <= t; ++kt) {
    const float* kpp = kp + (size_t)(kt << 4) * HSZ;
    f32x4 st = {0, 0, 0, 0};
#pragma unroll
    for (int c = 0; c < 4; ++c) {
      f32x4 kv = *(const f32x4*)(kpp + c * 16);
      bf16x4 bv;
#pragma unroll
      for (int j = 0; j < 4; ++j) bv[j] = (__bf16)kv[j];
      st = __builtin_amdgcn_mfma_f32_16x16x16bf16_1k(
               __builtin_bit_cast(s16x4, bv), qf[c], st, 0, 0, 0);
    }
    if (kt == t) {
#pragma unroll
      for (int r = 0; r < 4; ++r)
        if (g * 4 + r > lm) st[r] = -1e30f;
    }
    float tmax = fmaxf(fmaxf(st[0], st[1]), fmaxf(st[2], st[3]));
    tmax = fmaxf(tmax, __shfl_xor(tmax, 16));
    tmax = fmaxf(tmax, __shfl_xor(tmax, 32));
    const float mnew = fmaxf(m, tmax);
    const float fsc  = exp2f(m - mnew);
    f32x4 p;
#pragma unroll
    for (int r = 0; r < 4; ++r) p[r] = exp2f(st[r] - mnew);
    float tsum = (p[0] + p[1]) + (p[2] + p[3]);
    tsum += __shfl_xor(tsum, 16);
    tsum += __shfl_xor(tsum, 32);
    lsum = lsum * fsc + tsum;
    m = mnew;
#pragma unroll
    for (int nb = 0; nb < 4; ++nb)
#pragma unroll
      for (int r = 0; r < 4; ++r) oacc[nb][r] *= fsc;
    bf16x4 pb;
#pragma unroll
    for (int r = 0; r < 4; ++r) pb[r] = (__bf16)p[r];
    const s16x4 pf = __builtin_bit_cast(s16x4, pb);
    const float* vpp = vp + (size_t)(kt << 4) * HSZ;
#pragma unroll
    for (int nb = 0; nb < 4; ++nb) {
      bf16x4 vv;
#pragma unroll
      for (int j = 0; j < 4; ++j)
        vv[j] = (__bf16)vpp[(size_t)j * HSZ + nb * 16];
      oacc[nb] = __builtin_amdgcn_mfma_f32_16x16x16bf16_1k(
                     __builtin_bit_cast(s16x4, vv), pf, oacc[nb], 0, 0, 0);
    }
  }
  const float inv = 1.0f / lsum;
  float* op = Og + base + (size_t)(qb + lm) * HSZ + g * 4;
#pragma unroll
  for (int nb = 0; nb < 4; ++nb) {
    f32x4 o = oacc[nb];
#pragma unroll
    for (int r = 0; r < 4; ++r) o[r] *= inv;
    *(f32x4*)(op + nb * 16) = o;
  }
}

extern "C" void kernel_launch(void* const* d_in, const int* in_sizes, int n_in,
                              void* d_out, int out_size, void* d_ws, size_t ws_size,
                              hipStream_t stream) {
  const float* q = (const float*)d_in[0];
  const float* k = (const float*)d_in[1];
  const float* v = (const float*)d_in[2];
  float* o = (float*)d_out;
  const size_t elems = (size_t)2 * HH * SS * DD;     // 4,194,304 per tensor
  const size_t need  = 2 * elems * sizeof(short);    // Kf + Vf, 16.8 MB
  if (ws_size >= need) {
    short* Kf = (short*)d_ws;
    short* Vf = Kf + elems;
    prep_kv<<<6144, 256, 0, stream>>>(k, v, Kf, Vf);
    attn_fwd13<<<1024, 512, 0, stream>>>(q, Kf, Vf, o);
  } else {
    attn_fwd<<<dim3(32, 32), 256, 0, stream>>>(q, k, v, o);
  }
}

// Round 14
// 48.347 us; speedup vs baseline: 1.2251x; 1.2251x over previous
//
#include <hip/hip_runtime.h>

#define LOG2E 1.4426950408889634f
#define EXP2(x) __builtin_amdgcn_exp2f(x)   // bare v_exp_f32 (no ocml fixup)
#define MFMA32(a, b, c) __builtin_amdgcn_mfma_f32_32x32x16_bf16(a, b, c, 0, 0, 0)

typedef __attribute__((ext_vector_type(4)))  float f32x4;
typedef __attribute__((ext_vector_type(16))) float f32x16;
typedef __attribute__((ext_vector_type(8)))  short s16x8;
typedef __attribute__((ext_vector_type(4)))  short s16x4;
typedef __attribute__((ext_vector_type(4)))  __bf16 bf16x4;
typedef __attribute__((ext_vector_type(8)))  __bf16 bf16x8;

// B=2 S=2048 H=16 D=64, fp32 in/out.
#define SS 2048
#define HH 16
#define DD 64
#define HSZ (HH * DD)
#define BHSZ (SS * DD)  // 131072 elems per (b,h) plane

// ---- fused prep for 32x32 MFMA fragments ---------------------------------
// Kf[bh][sub(64)][c2(4)][lane][j(8)]: lane l -> K[key=sub*32+(l&31)]
//                                              [d = c2*16 + (l>>5)*8 + j]
// Vf[bh][sub(64)][db(2)][kh(2)][lane][j(8)]: lane l ->
//     V[key = sub*32 + kh*16 + (j&3)+8*(j>>2)+4*(l>>5)][d = db*32 + (l&31)]
// (kappa(c,j) = (j&3)+8*(j>>2)+4c matches the 32x32 C-output key pattern,
//  so QK's P registers feed PV's B operand directly, slot-for-slot.)
__global__ __launch_bounds__(256) void prep_kv(const float* __restrict__ Kg,
                                               const float* __restrict__ Vg,
                                               short* __restrict__ Kf,
                                               short* __restrict__ Vf) {
  const int blk = blockIdx.x;
  if (blk < 2048) {  // ---- K part: 524,288 16B chunks
    const int idx = blk * 256 + threadIdx.x;
    const int l   = idx & 63;
    const int c2  = (idx >> 6) & 3;
    const int sub = (idx >> 8) & 63;
    const int bh  = idx >> 14;
    const int b = bh >> 4, h = bh & 15;
    const int key = (sub << 5) + (l & 31);
    const int d0  = (c2 << 4) + ((l >> 5) << 3);
    const float* src = Kg + (((size_t)b * SS + key) * HH + h) * DD + d0;
    f32x4 a = *(const f32x4*)(src);
    f32x4 b2 = *(const f32x4*)(src + 4);
    bf16x8 o;
#pragma unroll
    for (int j = 0; j < 4; ++j) {
      o[j] = (__bf16)a[j];
      o[4 + j] = (__bf16)b2[j];
    }
    *(s16x8*)(Kf + (size_t)idx * 8) = __builtin_bit_cast(s16x8, o);
  } else {           // ---- V part: 524,288 16B chunks
    const int idx = (blk - 2048) * 256 + threadIdx.x;
    const int l   = idx & 63;
    const int kh  = (idx >> 6) & 1;
    const int db  = (idx >> 7) & 1;
    const int sub = (idx >> 8) & 63;
    const int bh  = idx >> 14;
    const int b = bh >> 4, h = bh & 15;
    const int d   = (db << 5) + (l & 31);
    const int hi4 = (l >> 5) << 2;
    const float* src = Vg + (((size_t)b * SS) * HH + h) * DD + d;
    bf16x8 o;
#pragma unroll
    for (int j = 0; j < 8; ++j) {
      const int key = (sub << 5) + (kh << 4) + ((j & 3) + ((j >> 2) << 3) + hi4);
      o[j] = (__bf16)src[(size_t)key * HSZ];
    }
    *(s16x8*)(Vf + (size_t)idx * 8) = __builtin_bit_cast(s16x8, o);
  }
}

// ---- main: 32x32-MFMA flash attention, R12 macro-structure ----------------
// 1024 blocks x 4 waves. Block = (bh, v): processes 32-row q-tile t=63-v
// then t=v sequentially; each pass: 4 waves split the key subtile range
// (32-key units) contiguously; pure-sum merge (static-base softmax, R9+);
// raw v_exp_f32 (R12). Per 32q x 32k unit: 4 QK mfma_32x32x16 + 4 PV
// (vs 12 16x16 mfma + 12 loads before) -> MFMA integral ~halved, loads
// ~1.5x fewer. P->PV needs NO cross-lane traffic: V fragments are packed
// with kappa(c,j) = the C-output key pattern. XCD-local bh, heavy-first.
// Launch bounds (256,4): cap 128 VGPR (watch spill tripwire; R7 lesson).

__device__ __forceinline__ void qtile_pass(
    const int t, const int w, const int lane,
    const float* __restrict__ Qg, const short* __restrict__ kb2,
    const short* __restrict__ vb2, float* __restrict__ Og,
    const size_t qbase, float (*lo)[33][64])
{
  const int lm31 = lane & 31;
  const int hi   = lane >> 5;
  const int n    = t + 1;                 // 32-key subtiles 0..t

  // Q fragment: q = t*32 + lm31, dims d = c2*16 + hi*8 + j, pre-scaled
  s16x8 qf[4];
  {
    const float qs = 0.125f * LOG2E;
    const float* qp = Qg + qbase + (size_t)((t << 5) + lm31) * HSZ + (hi << 3);
#pragma unroll
    for (int c2 = 0; c2 < 4; ++c2) {
      f32x4 a = *(const f32x4*)(qp + c2 * 16);
      f32x4 b2 = *(const f32x4*)(qp + c2 * 16 + 4);
      bf16x8 bv;
#pragma unroll
      for (int j = 0; j < 4; ++j) {
        bv[j] = (__bf16)(a[j] * qs);
        bv[4 + j] = (__bf16)(b2[j] * qs);
      }
      qf[c2] = __builtin_bit_cast(s16x8, bv);
    }
  }

  f32x16 oacc0 = {0,0,0,0,0,0,0,0,0,0,0,0,0,0,0,0};
  f32x16 oacc1 = {0,0,0,0,0,0,0,0,0,0,0,0,0,0,0,0};
  float lsum = 0.0f;

  // contiguous quarter [s, e) of subtiles for this wave
  const int n4 = n >> 2, rem = n & 3;
  int s = w * n4 + (w < rem ? w : rem);
  const int e = s + n4 + (w < rem ? 1 : 0);

  for (; s < e; ++s) {
    const short* ka = kb2 + ((size_t)s << 11);
    // ---- QK: S^T[key][q] via 4 x mfma 32x32x16 (staggered K loads)
    s16x8 k0 = *(const s16x8*)(ka);
    s16x8 k1 = *(const s16x8*)(ka + 512);
    f32x16 st = {0,0,0,0,0,0,0,0,0,0,0,0,0,0,0,0};
    st = MFMA32(k0, qf[0], st);
    st = MFMA32(k1, qf[1], st);
    s16x8 k2 = *(const s16x8*)(ka + 1024);
    s16x8 k3 = *(const s16x8*)(ka + 1536);
    st = MFMA32(k2, qf[2], st);
    st = MFMA32(k3, qf[3], st);
    // st[r] = score(key = s*32 + (r&3)+8*(r>>2)+4*hi, q = t*32 + lm31)
    if (s == t) {  // diagonal subtile: causal mask
#pragma unroll
      for (int r = 0; r < 16; ++r)
        if (((r & 3) + ((r >> 2) << 3) + (hi << 2)) > lm31) st[r] = -1e30f;
    }
    // ---- static-base softmax numerator + bf16 pack (B-operand order!)
    float p[16];
#pragma unroll
    for (int r = 0; r < 16; ++r) p[r] = EXP2(st[r]);
#pragma unroll
    for (int r = 0; r < 16; ++r) lsum += p[r];
    bf16x8 pb0, pb1;
#pragma unroll
    for (int r = 0; r < 8; ++r) {
      pb0[r] = (__bf16)p[r];
      pb1[r] = (__bf16)p[8 + r];
    }
    const s16x8 pf0 = __builtin_bit_cast(s16x8, pb0);
    const s16x8 pf1 = __builtin_bit_cast(s16x8, pb1);
    // ---- PV: OT[d][q] += V^T * P; A fragments match kappa slot-for-slot
    const short* vpp = vb2 + ((size_t)s << 11);
    s16x8 va00 = *(const s16x8*)(vpp);          // d-blk 0, keys 0..15
    s16x8 va01 = *(const s16x8*)(vpp + 512);    // d-blk 0, keys 16..31
    s16x8 va10 = *(const s16x8*)(vpp + 1024);   // d-blk 1, keys 0..15
    s16x8 va11 = *(const s16x8*)(vpp + 1536);   // d-blk 1, keys 16..31
    oacc0 = MFMA32(va00, pf0, oacc0);
    oacc0 = MFMA32(va01, pf1, oacc0);
    oacc1 = MFMA32(va10, pf0, oacc1);
    oacc1 = MFMA32(va11, pf1, oacc1);
  }

  // ---- 2-stage pure-sum merge; wave 0 normalizes and stores ----
  if (w == 1 || w == 3) {
    const int slot = w >> 1;
#pragma unroll
    for (int r = 0; r < 16; ++r) {
      lo[slot][r][lane] = oacc0[r];
      lo[slot][16 + r][lane] = oacc1[r];
    }
    lo[slot][32][lane] = lsum;
  }
  __syncthreads();
  if (w == 0) {
#pragma unroll
    for (int r = 0; r < 16; ++r) {
      oacc0[r] += lo[0][r][lane];
      oacc1[r] += lo[0][16 + r][lane];
    }
    lsum += lo[0][32][lane];
  }
  if (w == 2) {
#pragma unroll
    for (int r = 0; r < 16; ++r) {
      oacc0[r] += lo[1][r][lane];
      oacc1[r] += lo[1][16 + r][lane];
    }
    lsum += lo[1][32][lane];
#pragma unroll
    for (int r = 0; r < 16; ++r) {
      lo[1][r][lane] = oacc0[r];
      lo[1][16 + r][lane] = oacc1[r];
    }
    lo[1][32][lane] = lsum;
  }
  __syncthreads();
  if (w == 0) {
#pragma unroll
    for (int r = 0; r < 16; ++r) {
      oacc0[r] += lo[1][r][lane];
      oacc1[r] += lo[1][16 + r][lane];
    }
    lsum += lo[1][32][lane];
    float l = lsum + __shfl_xor(lsum, 32);
    const float inv = 1.0f / l;
    // out[q = t*32+lm31][d = db*32 + 8*q4 + 4*hi + (0..3)]
    float* op = Og + qbase + (size_t)((t << 5) + lm31) * HSZ + (hi << 2);
#pragma unroll
    for (int db = 0; db < 2; ++db)
#pragma unroll
      for (int q4 = 0; q4 < 4; ++q4) {
        f32x4 o;
#pragma unroll
        for (int j = 0; j < 4; ++j)
          o[j] = (db ? oacc1[q4 * 4 + j] : oacc0[q4 * 4 + j]) * inv;
        *(f32x4*)(op + db * 32 + q4 * 8) = o;
      }
  }
  __syncthreads();  // protect LDS slots before the next pass republishes
}

__global__ __launch_bounds__(256, 4) void attn_fwd14(
    const float* __restrict__ Qg, const short* __restrict__ Kf,
    const short* __restrict__ Vf, float* __restrict__ Og)
{
  __shared__ float lo[2][33][64];  // two publish slots [slot][reg][lane]

  const int tid  = threadIdx.x;
  const int lane = tid & 63;
  const int w    = tid >> 6;    // 0..3: split-K quarter

  // XCD-local mapping: id%8 = XCD (round-robin dispatch heuristic).
  const int id   = blockIdx.x;            // 0..1023
  const int xcd  = id & 7;
  const int r7   = id >> 3;               // 0..127
  const int bh   = (xcd << 2) | (r7 & 3);
  const int v    = r7 >> 2;               // 0..31
  const int tA   = 63 - v;                // heavy pass first
  const int tB   = v;                     // complementary light pass

  const size_t qbase = (size_t)(bh >> 4) * SS * HSZ + (size_t)(bh & 15) * DD;
  const short* kb2 = Kf + (size_t)bh * BHSZ + lane * 8;
  const short* vb2 = Vf + (size_t)bh * BHSZ + lane * 8;

  qtile_pass(tA, w, lane, Qg, kb2, vb2, Og, qbase, lo);
  qtile_pass(tB, w, lane, Qg, kb2, vb2, Og, qbase, lo);
}

// ---- fallback (round-1 kernel) if ws too small ---------------------------
__global__ __launch_bounds__(256) void attn_fwd(
    const float* __restrict__ Qg, const float* __restrict__ Kg,
    const float* __restrict__ Vg, float* __restrict__ Og)
{
  typedef __attribute__((ext_vector_type(4))) short s16x4v;
  const int tid  = threadIdx.x;
  const int lane = tid & 63;
  const int lm   = lane & 15;
  const int g    = lane >> 4;
  const int w    = tid >> 6;
  const int bh = blockIdx.x;
  const int b  = bh >> 4;
  const int h  = bh & 15;
  const int t  = ((gridDim.y - 1 - blockIdx.y) << 2) | w;
  const int qb = t << 4;
  const size_t base = (size_t)b * SS * HSZ + (size_t)h * DD;
  s16x4v qf[4];
  {
    const float* qp = Qg + base + (size_t)(qb + lm) * HSZ + g * 4;
    const float qs = 0.125f * LOG2E;
#pragma unroll
    for (int c = 0; c < 4; ++c) {
      f32x4 qv = *(const f32x4*)(qp + c * 16);
      bf16x4 bv;
#pragma unroll
      for (int j = 0; j < 4; ++j) bv[j] = (__bf16)(qv[j] * qs);
      qf[c] = __builtin_bit_cast(s16x4v, bv);
    }
  }
  f32x4 oacc[4] = {{0,0,0,0},{0,0,0,0},{0,0,0,0},{0,0,0,0}};
  float m = -1e30f, lsum = 0.0f;
  const float* kp = Kg + base + (size_t)lm * HSZ + g * 4;
  const float* vp = Vg + base + (size_t)(g * 4) * HSZ + lm;
  for (int kt = 0; kt <= t; ++kt) {
    const float* kpp = kp + (size_t)(kt << 4) * HSZ;
    f32x4 st = {0, 0, 0, 0};
#pragma unroll
    for (int c = 0; c < 4; ++c) {
      f32x4 kv = *(const f32x4*)(kpp + c * 16);
      bf16x4 bv;
#pragma unroll
      for (int j = 0; j < 4; ++j) bv[j] = (__bf16)kv[j];
      st = __builtin_amdgcn_mfma_f32_16x16x16bf16_1k(
               __builtin_bit_cast(s16x4v, bv), qf[c], st, 0, 0, 0);
    }
    if (kt == t) {
#pragma unroll
      for (int r = 0; r < 4; ++r)
        if (g * 4 + r > lm) st[r] = -1e30f;
    }
    float tmax = fmaxf(fmaxf(st[0], st[1]), fmaxf(st[2], st[3]));
    tmax = fmaxf(tmax, __shfl_xor(tmax, 16));
    tmax = fmaxf(tmax, __shfl_xor(tmax, 32));
    const float mnew = fmaxf(m, tmax);
    const float fsc  = exp2f(m - mnew);
    f32x4 p;
#pragma unroll
    for (int r = 0; r < 4; ++r) p[r] = exp2f(st[r] - mnew);
    float tsum = (p[0] + p[1]) + (p[2] + p[3]);
    tsum += __shfl_xor(tsum, 16);
    tsum += __shfl_xor(tsum, 32);
    lsum = lsum * fsc + tsum;
    m = mnew;
#pragma unroll
    for (int nb = 0; nb < 4; ++nb)
#pragma unroll
      for (int r = 0; r < 4; ++r) oacc[nb][r] *= fsc;
    bf16x4 pb;
#pragma unroll
    for (int r = 0; r < 4; ++r) pb[r] = (__bf16)p[r];
    const s16x4v pf = __builtin_bit_cast(s16x4v, pb);
    const float* vpp = vp + (size_t)(kt << 4) * HSZ;
#pragma unroll
    for (int nb = 0; nb < 4; ++nb) {
      bf16x4 vv;
#pragma unroll
      for (int j = 0; j < 4; ++j)
        vv[j] = (__bf16)vpp[(size_t)j * HSZ + nb * 16];
      oacc[nb] = __builtin_amdgcn_mfma_f32_16x16x16bf16_1k(
                     __builtin_bit_cast(s16x4v, vv), pf, oacc[nb], 0, 0, 0);
    }
  }
  const float inv = 1.0f / lsum;
  float* op = Og + base + (size_t)(qb + lm) * HSZ + g * 4;
#pragma unroll
  for (int nb = 0; nb < 4; ++nb) {
    f32x4 o = oacc[nb];
#pragma unroll
    for (int r = 0; r < 4; ++r) o[r] *= inv;
    *(f32x4*)(op + nb * 16) = o;
  }
}

extern "C" void kernel_launch(void* const* d_in, const int* in_sizes, int n_in,
                              void* d_out, int out_size, void* d_ws, size_t ws_size,
                              hipStream_t stream) {
  const float* q = (const float*)d_in[0];
  const float* k = (const float*)d_in[1];
  const float* v = (const float*)d_in[2];
  float* o = (float*)d_out;
  const size_t elems = (size_t)2 * HH * SS * DD;     // 4,194,304 per tensor
  const size_t need  = 2 * elems * sizeof(short);    // Kf + Vf, 16.8 MB
  if (ws_size >= need) {
    short* Kf = (short*)d_ws;
    short* Vf = Kf + elems;
    prep_kv<<<4096, 256, 0, stream>>>(k, v, Kf, Vf);
    attn_fwd14<<<1024, 256, 0, stream>>>(q, Kf, Vf, o);
  } else {
    attn_fwd<<<dim3(32, 32), 256, 0, stream>>>(q, k, v, o);
  }
}